// Round 1
// baseline (518.193 us; speedup 1.0000x reference)
//
#include <hip/hip_runtime.h>
#include <math.h>

// Problem constants
#define B_   128
#define K_   4
#define HW_  65536              // 256*256

constexpr int BLOCK = 256;
constexpr int NC    = 16;                   // chunks per b
constexpr int CHUNK = HW_ / NC;             // 4096 floats
constexpr int G     = CHUNK / 4 / BLOCK;    // 4 pipeline groups (1 float4/tensor each)

// Native clang vector type: __builtin_nontemporal_load requires a real
// vector (HIP's float4 is a struct and is rejected).
typedef float vfloat4 __attribute__((ext_vector_type(4)));

// Per-element math (t is exactly 0.0 or 1.0):
//   s   = sigmoid(x)
//   pt  = t*s + (1-t)*(1-s) = fma(t, 1-2s, s)   (true-class probability)
//   bce = -ln(pt); exp(-bce) == pt
//   focal += ALPHA * (1-pt)^2 * bce
// Native v_exp/v_rcp/v_log (quarter-rate) — rel err ~1e-6, threshold is 0.11.
__device__ __forceinline__ void proc_elem(float x, float t,
                                          float& fs, float& in, float& ps,
                                          float& i2, float& ms) {
    float e   = __expf(-fabsf(x));                 // e^{-|x|} (neg+abs are free mods)
    float inv = __builtin_amdgcn_rcpf(1.0f + e);   // sigmoid(|x|)
    bool  pos = (x >= 0.0f);
    float s   = pos ? inv : 1.0f - inv;            // sigmoid(x)
    float nms = fmaf(-2.0f, s, 1.0f);              // 1 - 2s
    float pt  = fmaf(t, nms, s);                   // prob of true class
    float l   = __logf(pt);                        // ln(pt) = -bce
    float om  = 1.0f - pt;
    fs = fmaf(om * om * l, -0.8f, fs);             // += ALPHA*(1-pt)^2*bce
    float pc  = fminf(fmaxf(s, 1e-4f), 0.9999f);   // clip(sigmoid) -> v_med3
    ps += pc;
    in  = fmaf(pc, t, in);
    float m = pos ? 1.0f : 0.0f;                   // mask (x >= 0)
    ms += m;
    i2  = fmaf(m, t, i2);
}

__device__ __forceinline__ void proc4(const vfloat4& xv, const vfloat4& tv,
                                      float& fs, float& in, float& ps,
                                      float& i2, float& ms) {
    proc_elem(xv.x, tv.x, fs, in, ps, i2, ms);
    proc_elem(xv.y, tv.y, fs, in, ps, i2, ms);
    proc_elem(xv.z, tv.z, fs, in, ps, i2, ms);
    proc_elem(xv.w, tv.w, fs, in, ps, i2, ms);
}

// Coherent (device-scope) load of cross-XCD atomic results.
__device__ __forceinline__ float gload(const float* p) {
    return __hip_atomic_load(p, __ATOMIC_RELAXED, __HIP_MEMORY_SCOPE_AGENT);
}

// Fully fused: per-(b,chunk) partial accumulation + threadfence/atomic-counter
// "last block finalizes" epilogue. Saves one dispatch + its graph gap vs the
// previous 3-dispatch (memset/partial/finalize) structure. Every input byte is
// still read exactly once chip-wide; launch_bounds(256,4) caps VGPR at 128
// (21 accumulators + 1-deep pipeline of 5 nontemporal float4 loads).
__global__ __launch_bounds__(BLOCK, 4) void fused_kernel(
    const float* __restrict__ pred_masks,   // B*K*HW
    const float* __restrict__ pred_ious,    // B*K
    const float* __restrict__ targets,      // B*HW
    float* __restrict__ ws,                 // 2688 partials + 1 counter (zeroed)
    float* __restrict__ out)                // [focal, dice, iou]
{
    float* __restrict__ fsum  = ws;             // B*K = 512
    float* __restrict__ inter = ws + 512;
    float* __restrict__ psum  = ws + 1024;
    float* __restrict__ i2s   = ws + 1536;
    float* __restrict__ msum  = ws + 2048;
    float* __restrict__ tsum  = ws + 2560;      // B = 128
    unsigned* __restrict__ counter = (unsigned*)(ws + 2688);

    const int blk = blockIdx.x;
    const int c   = blk & (NC - 1);
    const int b   = blk >> 4;               // NC == 16

    const vfloat4* __restrict__ t4 =
        reinterpret_cast<const vfloat4*>(targets + (size_t)b * HW_ + c * CHUNK);
    const float*  xb = pred_masks + (size_t)b * K_ * HW_ + c * CHUNK;
    const vfloat4* __restrict__ x0 = reinterpret_cast<const vfloat4*>(xb);
    const vfloat4* __restrict__ x1 = reinterpret_cast<const vfloat4*>(xb + HW_);
    const vfloat4* __restrict__ x2 = reinterpret_cast<const vfloat4*>(xb + 2 * HW_);
    const vfloat4* __restrict__ x3 = reinterpret_cast<const vfloat4*>(xb + 3 * HW_);

    float fs[K_] = {0.f, 0.f, 0.f, 0.f};
    float in[K_] = {0.f, 0.f, 0.f, 0.f};
    float ps[K_] = {0.f, 0.f, 0.f, 0.f};
    float i2[K_] = {0.f, 0.f, 0.f, 0.f};
    float ms[K_] = {0.f, 0.f, 0.f, 0.f};
    float ts = 0.f;

    int idx = threadIdx.x;
    vfloat4 tv  = __builtin_nontemporal_load(&t4[idx]);
    vfloat4 xv0 = __builtin_nontemporal_load(&x0[idx]);
    vfloat4 xv1 = __builtin_nontemporal_load(&x1[idx]);
    vfloat4 xv2 = __builtin_nontemporal_load(&x2[idx]);
    vfloat4 xv3 = __builtin_nontemporal_load(&x3[idx]);

    #pragma unroll
    for (int g = 0; g < G; ++g) {
        vfloat4 ntv, nx0, nx1, nx2, nx3;
        if (g < G - 1) {                    // compile-time resolved (unrolled)
            const int nidx = idx + BLOCK;
            ntv = __builtin_nontemporal_load(&t4[nidx]);
            nx0 = __builtin_nontemporal_load(&x0[nidx]);
            nx1 = __builtin_nontemporal_load(&x1[nidx]);
            nx2 = __builtin_nontemporal_load(&x2[nidx]);
            nx3 = __builtin_nontemporal_load(&x3[nidx]);
        }
        proc4(xv0, tv, fs[0], in[0], ps[0], i2[0], ms[0]);
        proc4(xv1, tv, fs[1], in[1], ps[1], i2[1], ms[1]);
        proc4(xv2, tv, fs[2], in[2], ps[2], i2[2], ms[2]);
        proc4(xv3, tv, fs[3], in[3], ps[3], i2[3], ms[3]);
        ts += tv.x + tv.y + tv.z + tv.w;
        if (g < G - 1) {
            idx += BLOCK;
            tv = ntv; xv0 = nx0; xv1 = nx1; xv2 = nx2; xv3 = nx3;
        }
    }

    // Pack 21 partials, wave-shuffle reduce (wave = 64), combine 4 waves via LDS.
    float vals[21];
    #pragma unroll
    for (int k = 0; k < K_; ++k) {
        vals[k]      = fs[k];
        vals[4 + k]  = in[k];
        vals[8 + k]  = ps[k];
        vals[12 + k] = i2[k];
        vals[16 + k] = ms[k];
    }
    vals[20] = ts;

    const int lane = threadIdx.x & 63;
    const int wave = threadIdx.x >> 6;

    #pragma unroll
    for (int v = 0; v < 21; ++v) {
        float x = vals[v];
        #pragma unroll
        for (int off = 32; off > 0; off >>= 1) x += __shfl_down(x, off, 64);
        vals[v] = x;
    }

    __shared__ float smem[21 * 4];
    if (lane == 0) {
        #pragma unroll
        for (int v = 0; v < 21; ++v) smem[v * 4 + wave] = vals[v];
    }
    __syncthreads();

    if (threadIdx.x < 21) {
        const int v = threadIdx.x;
        const float x = smem[v * 4 + 0] + smem[v * 4 + 1] +
                        smem[v * 4 + 2] + smem[v * 4 + 3];
        float* dst;
        if      (v < 4)  dst = &fsum[b * K_ + v];
        else if (v < 8)  dst = &inter[b * K_ + (v - 4)];
        else if (v < 12) dst = &psum[b * K_ + (v - 8)];
        else if (v < 16) dst = &i2s[b * K_ + (v - 12)];
        else if (v < 20) dst = &msum[b * K_ + (v - 16)];
        else             dst = &tsum[b];
        atomicAdd(dst, x);                  // device-scope on global by default
    }

    // --- completion counting: classic threadFenceReduction idiom ---
    __threadfence();                        // release our atomics device-wide
    __shared__ int lastf;
    __syncthreads();                        // order fences before the bump
    if (threadIdx.x == 0)
        lastf = (atomicAdd(counter, 1u) == (unsigned)(gridDim.x - 1)) ? 1 : 0;
    __syncthreads();
    if (!lastf) return;
    __threadfence();                        // acquire: invalidate stale lines

    // --- finalize: runs once, in the tail of the last resident block ---
    const float lo[K_] = {0.00f, 0.01f, 0.09f, 0.25f};
    const float hi[K_] = {0.04f, 0.16f, 0.49f, 1.00f};
    const float SMOOTH = 0.0001f;

    const int tb = threadIdx.x;             // threads 0..127 = one per sample
    float fA = 0.f, dA = 0.f, iA = 0.f, vbv = 0.f;
    if (tb < B_) {
        const float ts_ = gload(&tsum[tb]);
        const float ratio = ts_ * (1.0f / (float)HW_);
        float cnt = 0.f;
        #pragma unroll
        for (int k = 0; k < K_; ++k) {
            const bool valid = (ratio > lo[k]) && (ratio < hi[k]);
            if (valid) {
                cnt += 1.0f;
                fA += gload(&fsum[tb * K_ + k]) * (1.0f / (float)HW_);
                const float in_ = gload(&inter[tb * K_ + k]);
                const float ps_ = gload(&psum[tb * K_ + k]);
                dA += 1.0f - (2.0f * in_ + SMOOTH) / (ps_ + ts_ + SMOOTH);
                const float i2_ = gload(&i2s[tb * K_ + k]);
                const float ms_ = gload(&msum[tb * K_ + k]);
                const float gt  = (i2_ + SMOOTH) / (ms_ + ts_ - i2_ + SMOOTH);
                const float d   = pred_ious[tb * K_ + k] - gt;
                iA += d * d;
            }
        }
        const float invc = (cnt > 0.f) ? (1.0f / cnt) : 0.0f;
        fA *= invc; dA *= invc; iA *= invc;  // per_sample (0 when cnt==0)
        vbv = (cnt > 0.f) ? 1.0f : 0.0f;
    }

    // Reduce 4 quantities across the block (4 waves; threads >=128 carry 0).
    float v4[4] = {fA, dA, iA, vbv};
    #pragma unroll
    for (int v = 0; v < 4; ++v) {
        float x = v4[v];
        #pragma unroll
        for (int off = 32; off > 0; off >>= 1) x += __shfl_down(x, off, 64);
        v4[v] = x;
    }
    __shared__ float smem2[4 * 4];
    if (lane == 0) {
        #pragma unroll
        for (int v = 0; v < 4; ++v) smem2[v * 4 + wave] = v4[v];
    }
    __syncthreads();
    if (threadIdx.x == 0) {
        const float fT  = smem2[0]  + smem2[1]  + smem2[2]  + smem2[3];
        const float dT  = smem2[4]  + smem2[5]  + smem2[6]  + smem2[7];
        const float iT  = smem2[8]  + smem2[9]  + smem2[10] + smem2[11];
        const float vbT = smem2[12] + smem2[13] + smem2[14] + smem2[15];
        const float scale = (vbT > 0.f) ? (1.0f / vbT) : 1.0f;
        out[0] = 20.0f * fT * scale;   // FOCAL_W
        out[1] = dT * scale;           // DICE_W
        out[2] = iT * scale;           // IOU_W
    }
}

extern "C" void kernel_launch(void* const* d_in, const int* in_sizes, int n_in,
                              void* d_out, int out_size, void* d_ws, size_t ws_size,
                              hipStream_t stream) {
    const float* pred_masks = (const float*)d_in[0];   // B*K*HW
    const float* pred_ious  = (const float*)d_in[1];   // B*K
    const float* targets    = (const float*)d_in[2];   // B*HW
    float* out = (float*)d_out;
    float* ws  = (float*)d_ws;

    // 2688 partial floats + 1 completion counter
    (void)hipMemsetAsync(d_ws, 0, 2689 * sizeof(float), stream);

    fused_kernel<<<B_ * NC, BLOCK, 0, stream>>>(
        pred_masks, pred_ious, targets, ws, out);
}

// Round 2
// 212.337 us; speedup vs baseline: 2.4404x; 2.4404x over previous
//
#include <hip/hip_runtime.h>
#include <math.h>

// Problem constants
#define B_   128
#define K_   4
#define HW_  65536              // 256*256

constexpr int BLOCK = 256;
constexpr int NC    = 16;                   // chunks per b
constexpr int CHUNK = HW_ / NC;             // 4096 floats
constexpr int G     = CHUNK / 4 / BLOCK;    // 4 pipeline groups (1 float4/tensor each)
constexpr int NBLK  = B_ * NC;              // 2048 partial blocks
constexpr int NV    = 21;                   // partial values per block

// Native clang vector type: __builtin_nontemporal_load requires a real
// vector (HIP's float4 is a struct and is rejected).
typedef float vfloat4 __attribute__((ext_vector_type(4)));

// Per-element math (t is exactly 0.0 or 1.0):
//   s   = sigmoid(x)
//   pt  = t*s + (1-t)*(1-s) = fma(t, 1-2s, s)   (true-class probability)
//   bce = -ln(pt); exp(-bce) == pt
//   focal += ALPHA * (1-pt)^2 * bce
// Native v_exp/v_rcp/v_log (quarter-rate) — rel err ~1e-6, threshold is 0.11.
__device__ __forceinline__ void proc_elem(float x, float t,
                                          float& fs, float& in, float& ps,
                                          float& i2, float& ms) {
    float e   = __expf(-fabsf(x));                 // e^{-|x|} (neg+abs are free mods)
    float inv = __builtin_amdgcn_rcpf(1.0f + e);   // sigmoid(|x|)
    bool  pos = (x >= 0.0f);
    float s   = pos ? inv : 1.0f - inv;            // sigmoid(x)
    float nms = fmaf(-2.0f, s, 1.0f);              // 1 - 2s
    float pt  = fmaf(t, nms, s);                   // prob of true class
    float l   = __logf(pt);                        // ln(pt) = -bce
    float om  = 1.0f - pt;
    fs = fmaf(om * om * l, -0.8f, fs);             // += ALPHA*(1-pt)^2*bce
    float pc  = fminf(fmaxf(s, 1e-4f), 0.9999f);   // clip(sigmoid) -> v_med3
    ps += pc;
    in  = fmaf(pc, t, in);
    float m = pos ? 1.0f : 0.0f;                   // mask (x >= 0)
    ms += m;
    i2  = fmaf(m, t, i2);
}

__device__ __forceinline__ void proc4(const vfloat4& xv, const vfloat4& tv,
                                      float& fs, float& in, float& ps,
                                      float& i2, float& ms) {
    proc_elem(xv.x, tv.x, fs, in, ps, i2, ms);
    proc_elem(xv.y, tv.y, fs, in, ps, i2, ms);
    proc_elem(xv.z, tv.z, fs, in, ps, i2, ms);
    proc_elem(xv.w, tv.w, fs, in, ps, i2, ms);
}

// One block per (b, chunk). Every input byte is read exactly once chip-wide.
// launch_bounds(256,4) caps VGPR at 128: room for 21 accumulators + a 1-deep
// software pipeline of 5 nontemporal float4 loads (>=5 KB per wave in flight;
// Little's law for 6.3 TB/s needs only ~9 KB per CU).
//
// Each block writes its 21 partials to a UNIQUE slot ws[v*NBLK + blk] —
// every slot is written unconditionally, so no memset of the (poisoned)
// workspace is needed and no atomics are involved. Tail-only change vs the
// proven atomicAdd version; main loop untouched (codegen-fragile — the
// round-1 fused epilogue with fences collapsed VGPRs 128->36 and serialized
// the load pipeline).
__global__ __launch_bounds__(BLOCK, 4) void partial_kernel(
    const float* __restrict__ pred_masks,   // B*K*HW
    const float* __restrict__ targets,      // B*HW
    float* __restrict__ ws)                 // NV * NBLK partial slots
{
    const int blk = blockIdx.x;
    const int c   = blk & (NC - 1);
    const int b   = blk >> 4;               // NC == 16

    const vfloat4* __restrict__ t4 =
        reinterpret_cast<const vfloat4*>(targets + (size_t)b * HW_ + c * CHUNK);
    const float*  xb = pred_masks + (size_t)b * K_ * HW_ + c * CHUNK;
    const vfloat4* __restrict__ x0 = reinterpret_cast<const vfloat4*>(xb);
    const vfloat4* __restrict__ x1 = reinterpret_cast<const vfloat4*>(xb + HW_);
    const vfloat4* __restrict__ x2 = reinterpret_cast<const vfloat4*>(xb + 2 * HW_);
    const vfloat4* __restrict__ x3 = reinterpret_cast<const vfloat4*>(xb + 3 * HW_);

    float fs[K_] = {0.f, 0.f, 0.f, 0.f};
    float in[K_] = {0.f, 0.f, 0.f, 0.f};
    float ps[K_] = {0.f, 0.f, 0.f, 0.f};
    float i2[K_] = {0.f, 0.f, 0.f, 0.f};
    float ms[K_] = {0.f, 0.f, 0.f, 0.f};
    float ts = 0.f;

    int idx = threadIdx.x;
    vfloat4 tv  = __builtin_nontemporal_load(&t4[idx]);
    vfloat4 xv0 = __builtin_nontemporal_load(&x0[idx]);
    vfloat4 xv1 = __builtin_nontemporal_load(&x1[idx]);
    vfloat4 xv2 = __builtin_nontemporal_load(&x2[idx]);
    vfloat4 xv3 = __builtin_nontemporal_load(&x3[idx]);

    #pragma unroll
    for (int g = 0; g < G; ++g) {
        vfloat4 ntv, nx0, nx1, nx2, nx3;
        if (g < G - 1) {                    // compile-time resolved (unrolled)
            const int nidx = idx + BLOCK;
            ntv = __builtin_nontemporal_load(&t4[nidx]);
            nx0 = __builtin_nontemporal_load(&x0[nidx]);
            nx1 = __builtin_nontemporal_load(&x1[nidx]);
            nx2 = __builtin_nontemporal_load(&x2[nidx]);
            nx3 = __builtin_nontemporal_load(&x3[nidx]);
        }
        proc4(xv0, tv, fs[0], in[0], ps[0], i2[0], ms[0]);
        proc4(xv1, tv, fs[1], in[1], ps[1], i2[1], ms[1]);
        proc4(xv2, tv, fs[2], in[2], ps[2], i2[2], ms[2]);
        proc4(xv3, tv, fs[3], in[3], ps[3], i2[3], ms[3]);
        ts += tv.x + tv.y + tv.z + tv.w;
        if (g < G - 1) {
            idx += BLOCK;
            tv = ntv; xv0 = nx0; xv1 = nx1; xv2 = nx2; xv3 = nx3;
        }
    }

    // Pack 21 partials, wave-shuffle reduce (wave = 64), combine 4 waves via LDS.
    float vals[NV];
    #pragma unroll
    for (int k = 0; k < K_; ++k) {
        vals[k]      = fs[k];
        vals[4 + k]  = in[k];
        vals[8 + k]  = ps[k];
        vals[12 + k] = i2[k];
        vals[16 + k] = ms[k];
    }
    vals[20] = ts;

    const int lane = threadIdx.x & 63;
    const int wave = threadIdx.x >> 6;

    #pragma unroll
    for (int v = 0; v < NV; ++v) {
        float x = vals[v];
        #pragma unroll
        for (int off = 32; off > 0; off >>= 1) x += __shfl_down(x, off, 64);
        vals[v] = x;
    }

    __shared__ float smem[NV * 4];
    if (lane == 0) {
        #pragma unroll
        for (int v = 0; v < NV; ++v) smem[v * 4 + wave] = vals[v];
    }
    __syncthreads();

    if (threadIdx.x < NV) {
        const int v = threadIdx.x;
        const float x = smem[v * 4 + 0] + smem[v * 4 + 1] +
                        smem[v * 4 + 2] + smem[v * 4 + 3];
        // Transposed layout [v][b*NC + c]: finalize thread b reads 16
        // consecutive floats per v (4x vfloat4 from L2).
        ws[(size_t)v * NBLK + blk] = x;
    }
}

__global__ __launch_bounds__(128) void finalize_kernel(
    const float* __restrict__ pred_ious,    // B*K
    const float* __restrict__ ws,           // NV * NBLK partial slots
    float* __restrict__ out)                // [focal, dice, iou]
{
    const float lo[K_] = {0.00f, 0.01f, 0.09f, 0.25f};
    const float hi[K_] = {0.04f, 0.16f, 0.49f, 1.00f};
    const float SMOOTH = 0.0001f;

    const int b = threadIdx.x;              // 128 threads, one per sample

    // Sum each value over the 16 chunk slots (64 B aligned -> 4x vfloat4).
    float acc[NV];
    #pragma unroll
    for (int v = 0; v < NV; ++v) {
        const vfloat4* p =
            reinterpret_cast<const vfloat4*>(ws + (size_t)v * NBLK + b * NC);
        vfloat4 a = p[0];
        vfloat4 b4 = p[1];
        vfloat4 c4 = p[2];
        vfloat4 d4 = p[3];
        vfloat4 s = a + b4 + c4 + d4;
        acc[v] = s.x + s.y + s.z + s.w;
    }

    const float ts = acc[20];
    const float ratio = ts * (1.0f / (float)HW_);

    float cnt = 0.f, fA = 0.f, dA = 0.f, iA = 0.f;
    #pragma unroll
    for (int k = 0; k < K_; ++k) {
        const bool valid = (ratio > lo[k]) && (ratio < hi[k]);
        if (valid) {
            cnt += 1.0f;
            fA += acc[k] * (1.0f / (float)HW_);
            const float in_ = acc[4 + k];
            const float ps_ = acc[8 + k];
            dA += 1.0f - (2.0f * in_ + SMOOTH) / (ps_ + ts + SMOOTH);
            const float i2_ = acc[12 + k];
            const float ms_ = acc[16 + k];
            const float gt  = (i2_ + SMOOTH) / (ms_ + ts - i2_ + SMOOTH);
            const float d   = pred_ious[b * K_ + k] - gt;
            iA += d * d;
        }
    }
    const float invc = (cnt > 0.f) ? (1.0f / cnt) : 0.0f;
    fA *= invc; dA *= invc; iA *= invc;      // per_sample (0 when cnt==0)
    float vb = (cnt > 0.f) ? 1.0f : 0.0f;

    // Reduce 4 quantities across 128 threads (2 waves).
    float vals[4] = {fA, dA, iA, vb};
    const int lane = threadIdx.x & 63;
    const int wave = threadIdx.x >> 6;
    #pragma unroll
    for (int v = 0; v < 4; ++v) {
        float x = vals[v];
        #pragma unroll
        for (int off = 32; off > 0; off >>= 1) x += __shfl_down(x, off, 64);
        vals[v] = x;
    }
    __shared__ float smem[4 * 2];
    if (lane == 0) {
        #pragma unroll
        for (int v = 0; v < 4; ++v) smem[v * 2 + wave] = vals[v];
    }
    __syncthreads();
    if (threadIdx.x == 0) {
        const float fT  = smem[0] + smem[1];
        const float dT  = smem[2] + smem[3];
        const float iT  = smem[4] + smem[5];
        const float vbT = smem[6] + smem[7];
        const float scale = (vbT > 0.f) ? (1.0f / vbT) : 1.0f;
        out[0] = 20.0f * fT * scale;   // FOCAL_W
        out[1] = dT * scale;           // DICE_W
        out[2] = iT * scale;           // IOU_W
    }
}

extern "C" void kernel_launch(void* const* d_in, const int* in_sizes, int n_in,
                              void* d_out, int out_size, void* d_ws, size_t ws_size,
                              hipStream_t stream) {
    const float* pred_masks = (const float*)d_in[0];   // B*K*HW
    const float* pred_ious  = (const float*)d_in[1];   // B*K
    const float* targets    = (const float*)d_in[2];   // B*HW
    float* out = (float*)d_out;
    float* ws  = (float*)d_ws;   // NV*NBLK floats, every slot written each launch

    partial_kernel<<<NBLK, BLOCK, 0, stream>>>(pred_masks, targets, ws);
    finalize_kernel<<<1, 128, 0, stream>>>(pred_ious, ws, out);
}

// Round 3
// 211.387 us; speedup vs baseline: 2.4514x; 1.0045x over previous
//
#include <hip/hip_runtime.h>
#include <math.h>

// Problem constants
#define B_   128
#define K_   4
#define HW_  65536              // 256*256

constexpr int BLOCK = 256;
constexpr int NC    = 8;                    // chunks per b (grid = 1024 = 256 CU x 4 resident)
constexpr int CHUNK = HW_ / NC;             // 8192 floats
constexpr int G     = CHUNK / 4 / BLOCK;    // 8 pipeline groups (1 float4/tensor each)
constexpr int NBLK  = B_ * NC;              // 1024 partial blocks
constexpr int NV    = 21;                   // partial values per block

// Native clang vector type: __builtin_nontemporal_load requires a real
// vector (HIP's float4 is a struct and is rejected).
typedef float vfloat4 __attribute__((ext_vector_type(4)));

// Per-element math (t is exactly 0.0 or 1.0):
//   s   = sigmoid(x)
//   pt  = t*s + (1-t)*(1-s) = fma(t, 1-2s, s)   (true-class probability)
//   bce = -ln(pt); exp(-bce) == pt
//   focal += ALPHA * (1-pt)^2 * bce
// Native v_exp/v_rcp/v_log (quarter-rate) — rel err ~1e-6, threshold is 0.11.
__device__ __forceinline__ void proc_elem(float x, float t,
                                          float& fs, float& in, float& ps,
                                          float& i2, float& ms) {
    float e   = __expf(-fabsf(x));                 // e^{-|x|} (neg+abs are free mods)
    float inv = __builtin_amdgcn_rcpf(1.0f + e);   // sigmoid(|x|)
    bool  pos = (x >= 0.0f);
    float s   = pos ? inv : 1.0f - inv;            // sigmoid(x)
    float nms = fmaf(-2.0f, s, 1.0f);              // 1 - 2s
    float pt  = fmaf(t, nms, s);                   // prob of true class
    float l   = __logf(pt);                        // ln(pt) = -bce
    float om  = 1.0f - pt;
    fs = fmaf(om * om * l, -0.8f, fs);             // += ALPHA*(1-pt)^2*bce
    float pc  = fminf(fmaxf(s, 1e-4f), 0.9999f);   // clip(sigmoid) -> v_med3
    ps += pc;
    in  = fmaf(pc, t, in);
    float m = pos ? 1.0f : 0.0f;                   // mask (x >= 0)
    ms += m;
    i2  = fmaf(m, t, i2);
}

__device__ __forceinline__ void proc4(const vfloat4& xv, const vfloat4& tv,
                                      float& fs, float& in, float& ps,
                                      float& i2, float& ms) {
    proc_elem(xv.x, tv.x, fs, in, ps, i2, ms);
    proc_elem(xv.y, tv.y, fs, in, ps, i2, ms);
    proc_elem(xv.z, tv.z, fs, in, ps, i2, ms);
    proc_elem(xv.w, tv.w, fs, in, ps, i2, ms);
}

// One block per (b, chunk). Every input byte is read exactly once chip-wide.
// Grid = 1024 = 256 CU x 4 resident blocks: a SINGLE occupancy round (no
// inter-round drain bubble). Depth-2 software pipeline via 3 rotating
// register buffers: prefetch for group g+2 is issued BEFORE compute of
// group g, so each wave keeps ~10 KB in flight across two 832-cycle compute
// phases — covering HBM latency and keeping the memory pipe busy during
// compute (the round-0 depth-1 version serialized mem+compute: ~44 us vs
// the 26.6 us BW floor). All buffer indices are compile-time after full
// unroll (runtime-indexed vector arrays would spill to scratch).
__global__ __launch_bounds__(BLOCK, 4) void partial_kernel(
    const float* __restrict__ pred_masks,   // B*K*HW
    const float* __restrict__ targets,      // B*HW
    float* __restrict__ ws)                 // NV * NBLK partial slots
{
    const int blk = blockIdx.x;
    const int c   = blk & (NC - 1);
    const int b   = blk >> 3;               // NC == 8

    const vfloat4* __restrict__ t4 =
        reinterpret_cast<const vfloat4*>(targets + (size_t)b * HW_ + c * CHUNK);
    const float*  xb = pred_masks + (size_t)b * K_ * HW_ + c * CHUNK;
    const vfloat4* __restrict__ x0 = reinterpret_cast<const vfloat4*>(xb);
    const vfloat4* __restrict__ x1 = reinterpret_cast<const vfloat4*>(xb + HW_);
    const vfloat4* __restrict__ x2 = reinterpret_cast<const vfloat4*>(xb + 2 * HW_);
    const vfloat4* __restrict__ x3 = reinterpret_cast<const vfloat4*>(xb + 3 * HW_);

    float fs[K_] = {0.f, 0.f, 0.f, 0.f};
    float in[K_] = {0.f, 0.f, 0.f, 0.f};
    float ps[K_] = {0.f, 0.f, 0.f, 0.f};
    float i2[K_] = {0.f, 0.f, 0.f, 0.f};
    float ms[K_] = {0.f, 0.f, 0.f, 0.f};
    float ts = 0.f;

    // 3 rotating prefetch buffers (slot = g % 3, compile-time after unroll).
    vfloat4 T[3], A0[3], A1[3], A2[3], A3[3];

    const int tid = threadIdx.x;
    // Prologue: groups 0 and 1 in flight.
    T[0]  = __builtin_nontemporal_load(&t4[tid]);
    A0[0] = __builtin_nontemporal_load(&x0[tid]);
    A1[0] = __builtin_nontemporal_load(&x1[tid]);
    A2[0] = __builtin_nontemporal_load(&x2[tid]);
    A3[0] = __builtin_nontemporal_load(&x3[tid]);
    T[1]  = __builtin_nontemporal_load(&t4[tid + BLOCK]);
    A0[1] = __builtin_nontemporal_load(&x0[tid + BLOCK]);
    A1[1] = __builtin_nontemporal_load(&x1[tid + BLOCK]);
    A2[1] = __builtin_nontemporal_load(&x2[tid + BLOCK]);
    A3[1] = __builtin_nontemporal_load(&x3[tid + BLOCK]);

    #pragma unroll
    for (int g = 0; g < G; ++g) {
        const int cur = g % 3;
        if (g + 2 < G) {                     // compile-time resolved (unrolled)
            const int pf   = (g + 2) % 3;
            const int nidx = tid + (g + 2) * BLOCK;
            T[pf]  = __builtin_nontemporal_load(&t4[nidx]);
            A0[pf] = __builtin_nontemporal_load(&x0[nidx]);
            A1[pf] = __builtin_nontemporal_load(&x1[nidx]);
            A2[pf] = __builtin_nontemporal_load(&x2[nidx]);
            A3[pf] = __builtin_nontemporal_load(&x3[nidx]);
        }
        proc4(A0[cur], T[cur], fs[0], in[0], ps[0], i2[0], ms[0]);
        proc4(A1[cur], T[cur], fs[1], in[1], ps[1], i2[1], ms[1]);
        proc4(A2[cur], T[cur], fs[2], in[2], ps[2], i2[2], ms[2]);
        proc4(A3[cur], T[cur], fs[3], in[3], ps[3], i2[3], ms[3]);
        ts += T[cur].x + T[cur].y + T[cur].z + T[cur].w;
    }

    // Pack 21 partials, wave-shuffle reduce (wave = 64), combine 4 waves via LDS.
    float vals[NV];
    #pragma unroll
    for (int k = 0; k < K_; ++k) {
        vals[k]      = fs[k];
        vals[4 + k]  = in[k];
        vals[8 + k]  = ps[k];
        vals[12 + k] = i2[k];
        vals[16 + k] = ms[k];
    }
    vals[20] = ts;

    const int lane = threadIdx.x & 63;
    const int wave = threadIdx.x >> 6;

    #pragma unroll
    for (int v = 0; v < NV; ++v) {
        float x = vals[v];
        #pragma unroll
        for (int off = 32; off > 0; off >>= 1) x += __shfl_down(x, off, 64);
        vals[v] = x;
    }

    __shared__ float smem[NV * 4];
    if (lane == 0) {
        #pragma unroll
        for (int v = 0; v < NV; ++v) smem[v * 4 + wave] = vals[v];
    }
    __syncthreads();

    if (threadIdx.x < NV) {
        const int v = threadIdx.x;
        const float x = smem[v * 4 + 0] + smem[v * 4 + 1] +
                        smem[v * 4 + 2] + smem[v * 4 + 3];
        // Transposed layout [v][b*NC + c]: finalize thread b reads 8
        // consecutive floats per v (2x vfloat4 from L2). Every slot is
        // written unconditionally -> no workspace memset needed.
        ws[(size_t)v * NBLK + blk] = x;
    }
}

__global__ __launch_bounds__(128) void finalize_kernel(
    const float* __restrict__ pred_ious,    // B*K
    const float* __restrict__ ws,           // NV * NBLK partial slots
    float* __restrict__ out)                // [focal, dice, iou]
{
    const float lo[K_] = {0.00f, 0.01f, 0.09f, 0.25f};
    const float hi[K_] = {0.04f, 0.16f, 0.49f, 1.00f};
    const float SMOOTH = 0.0001f;

    const int b = threadIdx.x;              // 128 threads, one per sample

    // Sum each value over the 8 chunk slots (32 B aligned -> 2x vfloat4).
    float acc[NV];
    #pragma unroll
    for (int v = 0; v < NV; ++v) {
        const vfloat4* p =
            reinterpret_cast<const vfloat4*>(ws + (size_t)v * NBLK + b * NC);
        vfloat4 a  = p[0];
        vfloat4 b4 = p[1];
        vfloat4 s  = a + b4;
        acc[v] = s.x + s.y + s.z + s.w;
    }

    const float ts = acc[20];
    const float ratio = ts * (1.0f / (float)HW_);

    float cnt = 0.f, fA = 0.f, dA = 0.f, iA = 0.f;
    #pragma unroll
    for (int k = 0; k < K_; ++k) {
        const bool valid = (ratio > lo[k]) && (ratio < hi[k]);
        if (valid) {
            cnt += 1.0f;
            fA += acc[k] * (1.0f / (float)HW_);
            const float in_ = acc[4 + k];
            const float ps_ = acc[8 + k];
            dA += 1.0f - (2.0f * in_ + SMOOTH) / (ps_ + ts + SMOOTH);
            const float i2_ = acc[12 + k];
            const float ms_ = acc[16 + k];
            const float gt  = (i2_ + SMOOTH) / (ms_ + ts - i2_ + SMOOTH);
            const float d   = pred_ious[b * K_ + k] - gt;
            iA += d * d;
        }
    }
    const float invc = (cnt > 0.f) ? (1.0f / cnt) : 0.0f;
    fA *= invc; dA *= invc; iA *= invc;      // per_sample (0 when cnt==0)
    float vb = (cnt > 0.f) ? 1.0f : 0.0f;

    // Reduce 4 quantities across 128 threads (2 waves).
    float vals[4] = {fA, dA, iA, vb};
    const int lane = threadIdx.x & 63;
    const int wave = threadIdx.x >> 6;
    #pragma unroll
    for (int v = 0; v < 4; ++v) {
        float x = vals[v];
        #pragma unroll
        for (int off = 32; off > 0; off >>= 1) x += __shfl_down(x, off, 64);
        vals[v] = x;
    }
    __shared__ float smem[4 * 2];
    if (lane == 0) {
        #pragma unroll
        for (int v = 0; v < 4; ++v) smem[v * 2 + wave] = vals[v];
    }
    __syncthreads();
    if (threadIdx.x == 0) {
        const float fT  = smem[0] + smem[1];
        const float dT  = smem[2] + smem[3];
        const float iT  = smem[4] + smem[5];
        const float vbT = smem[6] + smem[7];
        const float scale = (vbT > 0.f) ? (1.0f / vbT) : 1.0f;
        out[0] = 20.0f * fT * scale;   // FOCAL_W
        out[1] = dT * scale;           // DICE_W
        out[2] = iT * scale;           // IOU_W
    }
}

extern "C" void kernel_launch(void* const* d_in, const int* in_sizes, int n_in,
                              void* d_out, int out_size, void* d_ws, size_t ws_size,
                              hipStream_t stream) {
    const float* pred_masks = (const float*)d_in[0];   // B*K*HW
    const float* pred_ious  = (const float*)d_in[1];   // B*K
    const float* targets    = (const float*)d_in[2];   // B*HW
    float* out = (float*)d_out;
    float* ws  = (float*)d_ws;   // NV*NBLK floats, every slot written each launch

    partial_kernel<<<NBLK, BLOCK, 0, stream>>>(pred_masks, targets, ws);
    finalize_kernel<<<1, 128, 0, stream>>>(pred_ious, ws, out);
}